// Round 8
// baseline (153.138 us; speedup 1.0000x reference)
//
#include <hip/hip_runtime.h>

typedef _Float16 half_t;
typedef _Float16 v8h __attribute__((ext_vector_type(8)));
typedef _Float16 v4h __attribute__((ext_vector_type(4)));
typedef float v4f __attribute__((ext_vector_type(4)));

#define XTP 40   // xt LDS row pitch (halves): 32 data + 8 pad (16B-aligned rows)
#define HP  72   // h  LDS row pitch (halves): 64 data + 8 pad (16B-aligned rows)

typedef __attribute__((address_space(3))) unsigned int lds_u32;
typedef const __attribute__((address_space(1))) unsigned int glb_u32;

// async 16B/lane global->LDS DMA: lds dest = l + lane*16 (HW), src = g + lane*16
__device__ __forceinline__ void dma16(const half_t* g, half_t* l, int lane) {
  __builtin_amdgcn_global_load_lds((glb_u32*)(g + lane * 8), (lds_u32*)(l), 16, 0, 0);
}

// raw waitcnt: vmcnt(N), lgkmcnt/expcnt = no-wait (gfx9 encoding)
#define WAITVM(N) __builtin_amdgcn_s_waitcnt(0xF70 | (N))
#define SCHED0()  __builtin_amdgcn_sched_barrier(0)

// ===== W prep: W (128,K) f32 -> f16 chunked [K/8][128][8], load-coalesced =====
__global__ __launch_bounds__(256) void prep_w_all(const float* __restrict__ W0,
                                                  const float* __restrict__ W1,
                                                  const float* __restrict__ W2,
                                                  half_t* __restrict__ w0h,
                                                  half_t* __restrict__ w1h,
                                                  half_t* __restrict__ w2h) {
  int i = blockIdx.x * 256 + threadIdx.x;   // 0..81919
  const float* src; half_t* dst; int o, k8, ktot;
  if (i < 16384)      { o = i >> 7;               k8 = i & 127;               src = W0; dst = w0h; ktot = 1024; }
  else if (i < 49152) { int j = i - 16384; o = j >> 8; k8 = j & 255;          src = W1; dst = w1h; ktot = 2048; }
  else                { int j = i - 49152; o = j >> 8; k8 = j & 255;          src = W2; dst = w2h; ktot = 2048; }
  const float* s = src + (size_t)o * ktot + k8 * 8;   // consecutive lanes: consecutive k8 -> coalesced
  float4 f0 = *(const float4*)s;
  float4 f1 = *(const float4*)(s + 4);
  union { half_t h[8]; uint4 u; } pk;
  pk.h[0] = (half_t)f0.x; pk.h[1] = (half_t)f0.y; pk.h[2] = (half_t)f0.z; pk.h[3] = (half_t)f0.w;
  pk.h[4] = (half_t)f1.x; pk.h[5] = (half_t)f1.y; pk.h[6] = (half_t)f1.z; pk.h[7] = (half_t)f1.w;
  *(uint4*)(dst + (size_t)(k8 * 128 + o) * 8) = pk.u;
}

// ===== one quad = 8 K32-steps of the DMA-ring K-loop (ring rotation period 4 -> identity/quad) =====
template <int G, int NSEL, bool TAIL>
__device__ __forceinline__ void run_quad(const half_t* __restrict__ wgt, int sbase,
                                         half_t* (&r)[4], int wv, int lane, int arow,
                                         const half_t* __restrict__ xt_lds, const int (&lrow)[4],
                                         const v8h (&hreg)[4][NSEL], v4f (&acc)[2][4]) {
  v8h xv8[4]; v4h xv4[4];
  if (G == 64) {
#pragma unroll
    for (int ni = 0; ni < 4; ++ni) xv4[ni] = *(const v4h*)(xt_lds + lrow[ni] * XTP + (sbase >> 1));
  } else {
#pragma unroll
    for (int ni = 0; ni < 4; ++ni) xv8[ni] = *(const v8h*)(xt_lds + lrow[ni] * XTP + sbase);
  }
#pragma unroll
  for (int i = 0; i < 8; ++i) {
    SCHED0();
    if (!TAIL || i <= 5) { WAITVM(2); } else if (i == 6) { WAITVM(1); } else { WAITVM(0); }
    __builtin_amdgcn_s_barrier();
    SCHED0();
    if (!TAIL || i <= 4)   // prefetch slab s+3 (depth-3)
      dma16(wgt + (size_t)(sbase + i + 3) * 4096 + wv * 512, r[3] + wv * 512, lane);
    const int sel = (G == 64) ? (i & 1) : 0;
    v8h a0 = *(const v8h*)(r[0] + arow);
    v8h a1 = *(const v8h*)(r[0] + arow + 128);
    v8h bfr[4];
#pragma unroll
    for (int ni = 0; ni < 4; ++ni) {
      half_t xs = (G == 64) ? xv4[ni][i >> 1] : xv8[ni][i];
      bfr[ni] = hreg[ni][sel] * xs;                       // Z fragment: x0[f,e]*h[g,e]
    }
#pragma unroll
    for (int ni = 0; ni < 4; ++ni)
      acc[0][ni] = __builtin_amdgcn_mfma_f32_16x16x32_f16(a0, bfr[ni], acc[0][ni], 0, 0, 0);
#pragma unroll
    for (int ni = 0; ni < 4; ++ni)
      acc[1][ni] = __builtin_amdgcn_mfma_f32_16x16x32_f16(a1, bfr[ni], acc[1][ni], 0, 0, 0);
    half_t* t = r[0]; r[0] = r[1]; r[1] = r[2]; r[2] = r[3]; r[3] = t;
  }
}

// ============ one CIN layer (device). Wave tile 32(o) x 64(4 batch x 16 e). ============
// 8 waves: m-pos = wv&3 (4x32 = 128 o), n-pos = wv>>2 (2x64 = 8 batch).
// A-redundancy 2x (was 4x in R7): per wave per step only 2 ds_read_b128.
template <int G, int KTOT, int KEEP, int OUT_BASE, bool H_OUT, bool H_IS_X>
__device__ __forceinline__ void layer(const half_t* __restrict__ wgt,
                                      const float* __restrict__ bias,
                                      half_t* __restrict__ xt_lds,
                                      half_t* __restrict__ h_lds,
                                      half_t* __restrict__ w_ring,
                                      float* __restrict__ out,
                                      size_t b0, int tid) {
  constexpr int NS = KTOT / 32;
  constexpr int NQ = NS / 8;
  constexpr int NSEL = (G == 64) ? 2 : 1;
  const int lane = tid & 63;
  const int wv = tid >> 6;
  const int wm = (wv & 3) * 32;        // o offset of wave
  const int wb = (wv >> 2) * 4;        // batch offset (0 or 4)
  const int col = lane & 15;           // = e
  const int kq = lane >> 4;            // k-quad (fixed per lane)
  const int arow = (kq * 128 + wm + col) * 8;   // A-frag offset in slab (halves)

  int lrow[4];
#pragma unroll
  for (int ni = 0; ni < 4; ++ni) lrow[ni] = (wb + ni) * 16 + col;

  __syncthreads();   // full drain: prev layer's h_lds/out/bias VMEM + staging visible

  const half_t* hb = H_IS_X ? xt_lds : h_lds;
  const int hpitch = H_IS_X ? XTP : HP;
  v8h hreg[4][NSEL];
#pragma unroll
  for (int ni = 0; ni < 4; ++ni) {
    const half_t* hp = hb + lrow[ni] * hpitch + kq * 8;
    hreg[ni][0] = *(const v8h*)hp;
    if (NSEL > 1) hreg[ni][NSEL - 1] = *(const v8h*)(hp + 32);
  }

  // prologue: DMA slabs 0..2 (1 dma16 = 1KB per wave per 8KB slab)
#pragma unroll
  for (int p = 0; p < 3; ++p)
    dma16(wgt + (size_t)p * 4096 + wv * 512, w_ring + p * 4096 + wv * 512, lane);

  half_t* r[4] = {w_ring, w_ring + 4096, w_ring + 8192, w_ring + 12288};
  v4f acc[2][4] = {};

#pragma unroll 1
  for (int q = 0; q < NQ - 1; ++q)
    run_quad<G, NSEL, false>(wgt, q * 8, r, wv, lane, arow, xt_lds, lrow, hreg, acc);
  run_quad<G, NSEL, true>(wgt, (NQ - 1) * 8, r, wv, lane, arow, xt_lds, lrow, hreg, acc);

  // ---- epilogue: bias + relu; rows>=64 -> h_lds; rows<KEEP -> sum_e -> out ----
  // No barrier needed: no wave reads xt/h_lds after its entry phase (next layer syncs).
#pragma unroll
  for (int mi = 0; mi < 2; ++mi) {
    const int o_base = wm + mi * 16 + kq * 4;
    float4 b4 = *(const float4*)(bias + o_base);
#pragma unroll
    for (int ni = 0; ni < 4; ++ni) {
      const int bb = wb + ni;
      float v[4];
#pragma unroll
      for (int r2 = 0; r2 < 4; ++r2)
        v[r2] = fmaxf(acc[mi][ni][r2] + (&b4.x)[r2], 0.0f);
      if (H_OUT && o_base >= 64) {       // uniform per (wave,mi)
        union { half_t h[4]; uint2 u; } pk;
#pragma unroll
        for (int r2 = 0; r2 < 4; ++r2) pk.h[r2] = (half_t)v[r2];
        *(uint2*)(h_lds + (bb * 16 + col) * HP + (o_base - 64)) = pk.u;
      }
      if (o_base < KEEP) {               // uniform per (wave,mi)
#pragma unroll
        for (int r2 = 0; r2 < 4; ++r2) {
          float sv = v[r2];
          sv += __shfl_xor(sv, 1);
          sv += __shfl_xor(sv, 2);
          sv += __shfl_xor(sv, 4);
          sv += __shfl_xor(sv, 8);       // sum over e (16-lane group)
          if (col == 0) out[(b0 + bb) * 256 + OUT_BASE + o_base + r2] = sv;
        }
      }
    }
  }
}

// ============ fused CIN: all 3 layers, one block = 8 batch elements ============
// 512 thr (8 waves), grid 512 -> 2 blocks/CU -> 4 waves/SIMD. LDS 60KB -> 120KB/CU.
__global__ __launch_bounds__(512, 4) void cin_fused(const float* __restrict__ x,
                                                    const half_t* __restrict__ w0h,
                                                    const half_t* __restrict__ w1h,
                                                    const half_t* __restrict__ w2h,
                                                    const float* __restrict__ b0p,
                                                    const float* __restrict__ b1p,
                                                    const float* __restrict__ b2p,
                                                    float* __restrict__ out) {
  __shared__ __align__(16) half_t xt_lds[128 * XTP];
  __shared__ __align__(16) half_t h_lds[128 * HP];
  __shared__ __align__(16) half_t w_ring[4 * 4096];

  const int tid = threadIdx.x;
  const size_t b0 = (size_t)blockIdx.x * 8;

  // ---- stage xt from x f32 (b,f,e) -> LDS (b,e) rows x 32 f, f16 ----
#pragma unroll
  for (int i = 0; i < 2; ++i) {
    int idx = (i * 512 + tid) * 4;
    float4 v = *(const float4*)(x + b0 * 512 + idx);
    int e = idx & 15, f = (idx >> 4) & 31, b = idx >> 9;
    half_t* d = xt_lds + (b * 16 + e) * XTP + f;
    d[0 * XTP] = (half_t)v.x;
    d[1 * XTP] = (half_t)v.y;
    d[2 * XTP] = (half_t)v.z;
    d[3 * XTP] = (half_t)v.w;
  }

  layer<32, 1024, 64, 0, true, true>(w0h, b0p, xt_lds, h_lds, w_ring, out, b0, tid);
  layer<64, 2048, 64, 64, true, false>(w1h, b1p, xt_lds, h_lds, w_ring, out, b0, tid);
  layer<64, 2048, 128, 128, false, false>(w2h, b2p, xt_lds, h_lds, w_ring, out, b0, tid);
}

extern "C" void kernel_launch(void* const* d_in, const int* in_sizes, int n_in,
                              void* d_out, int out_size, void* d_ws, size_t ws_size,
                              hipStream_t stream) {
  const float* x  = (const float*)d_in[0];
  const float* W0 = (const float*)d_in[1];
  const float* b0 = (const float*)d_in[2];
  const float* W1 = (const float*)d_in[3];
  const float* b1 = (const float*)d_in[4];
  const float* W2 = (const float*)d_in[5];
  const float* b2 = (const float*)d_in[6];
  float* out = (float*)d_out;
  char* ws = (char*)d_ws;

  half_t* w0h = (half_t*)(ws);                       // 256 KB
  half_t* w1h = (half_t*)(ws + (256u << 10));        // 512 KB
  half_t* w2h = (half_t*)(ws + (768u << 10));        // 512 KB

  prep_w_all<<<320, 256, 0, stream>>>(W0, W1, W2, w0h, w1h, w2h);
  cin_fused<<<512, 512, 0, stream>>>(x, w0h, w1h, w2h, b0, b1, b2, out);
}